// Round 6
// baseline (328.262 us; speedup 1.0000x reference)
//
#include <hip/hip_runtime.h>
#include <hip/hip_bf16.h>
#include <stdint.h>

// KANLinear fused MFMA GEMM, R6: A-side LDS eliminated.
//   C = A @ W^T, A (B x 2304) = [silu(x) | cubic bspline bases(x)], W in ws (bf16).
// Basis A-fragments are gathered DIRECTLY into MFMA A-operand registers from a
// direct-indexed uint4 table (one entry = all 8 coefs of one input, 16B), built in
// build_w. idx = floor(320*x + 704) + 1, clamped; entry 0 / 1409 = zeros.
// Bs (weights) double-buffered via global_load_lds DMA, XOR-swizzled (0-conflict).

#define IN_F 256
#define OUT_F 256
#define KDIM 2304
#define BK 64
#define NCHUNK 36
#define TENT 1410
#define WC_BYTES ((size_t)OUT_F * KDIM * 2) /* 1,179,648 */

#define AS1 __attribute__((address_space(1)))
#define AS3 __attribute__((address_space(3)))

typedef float f32x4 __attribute__((ext_vector_type(4)));
typedef short bf16x8 __attribute__((ext_vector_type(8)));

union U4B8 { uint4 u; bf16x8 v; };

__device__ __forceinline__ uint32_t f2bf(float f) {
    union { float f; uint32_t u; } c; c.f = f;
    uint32_t u = c.u;
    return (u + 0x7FFFu + ((u >> 16) & 1u)) >> 16;   // RNE
}

__device__ __forceinline__ float silu_f(float v) {
    return v / (1.0f + __expf(-v));
}

// ---------------- kernel 1: combined bf16 weight + direct basis table ----------------
__global__ void build_w(const float* __restrict__ bw, const float* __restrict__ sw,
                        const float* __restrict__ ss, unsigned short* __restrict__ Wc,
                        uint4* __restrict__ T) {
    const int o = blockIdx.x;
    const int i = threadIdx.x;
    Wc[o * KDIM + i] = (unsigned short)f2bf(bw[o * IN_F + i]);
    const float scal = ss[o * IN_F + i];
    const float4* swv = reinterpret_cast<const float4*>(sw + (size_t)(o * IN_F + i) * 8);
    float4 s0 = swv[0], s1 = swv[1];
    uint4 wv;
    wv.x = f2bf(s0.x * scal) | (f2bf(s0.y * scal) << 16);
    wv.y = f2bf(s0.z * scal) | (f2bf(s0.w * scal) << 16);
    wv.z = f2bf(s1.x * scal) | (f2bf(s1.y * scal) << 16);
    wv.w = f2bf(s1.z * scal) | (f2bf(s1.w * scal) << 16);
    *reinterpret_cast<uint4*>(Wc + o * KDIM + IN_F + i * 8) = wv;

    if (o == 0) {
        for (int e = i; e < TENT; e += IN_F) {
            uint4 ent = make_uint4(0, 0, 0, 0);
            if (e > 0 && e < 1409) {
                int v = e - 1;
                int j0 = v >> 7;                       // cell index 0..10
                float t = ((v & 127) + 0.5f) * (1.0f / 128.0f);
                float t2 = t * t, t3 = t2 * t;
                float p3 = t3 * (1.0f / 6.0f);                                // coef j0
                float p2 = -0.5f * t3 + 0.5f * t2 + 0.5f * t + (1.0f / 6.0f); // j0-1
                float p1 = 0.5f * t3 - t2 + (2.0f / 3.0f);                    // j0-2
                float omt = 1.0f - t;
                float p0 = omt * omt * omt * (1.0f / 6.0f);                   // j0-3
                uint32_t h[8];
                for (int j = 0; j < 8; ++j) {
                    int sdx = j0 - j;
                    float val = (sdx == 0) ? p3 : (sdx == 1) ? p2
                              : (sdx == 2) ? p1 : (sdx == 3) ? p0 : 0.0f;
                    h[j] = f2bf(val);
                }
                ent.x = h[0] | (h[1] << 16);
                ent.y = h[2] | (h[3] << 16);
                ent.z = h[4] | (h[5] << 16);
                ent.w = h[6] | (h[7] << 16);
            }
            T[e] = ent;
        }
    }
}

// ---------------- kernel 2: fused GEMM, direct-register A-fragments ----------------
#define TBL_IDX(xx, dst) { \
    float _u = __builtin_fmaf((xx), 320.0f, 704.0f); \
    _u = fminf(fmaxf(_u, -1.0f), 1408.0f); \
    dst = (int)floorf(_u) + 1; }

#define STAGE_B(KC1, BSN) { \
    __builtin_amdgcn_global_load_lds((const AS1 void*)(wbase0 + (KC1) * 128), \
        (AS3 void*)&BSN[ldst0], 16, 0, 0); \
    __builtin_amdgcn_global_load_lds((const AS1 void*)(wbase1 + (KC1) * 128), \
        (AS3 void*)&BSN[ldst1], 16, 0, 0); }

#define PREFETCH_A(KC1, AFN) { \
    const int _i0 = ((KC1) - 4) * 8; \
    _Pragma("unroll") \
    for (int _mt = 0; _mt < 4; ++_mt) { \
      float _x0 = xbq[_mt * 4096 + _i0]; \
      float _x1 = xbq[_mt * 4096 + _i0 + 4]; \
      int _t0, _t1; \
      TBL_IDX(_x0, _t0) \
      TBL_IDX(_x1, _t1) \
      AFN[_mt] = T8[_t0]; \
      AFN[_mt + 4] = T8[_t1]; \
    } }

#define CHUNK(KC, BSC, BSN, AFC, AFN) { \
    if ((KC) + 1 < NCHUNK) { \
      STAGE_B((KC) + 1, BSN) \
      if ((KC) + 1 >= 4) PREFETCH_A((KC) + 1, AFN) \
    } \
    if ((KC) < 4) { \
      _Pragma("unroll") \
      for (int _f = 0; _f < 8; ++_f) { \
        const float* _xp = xsl + (_f & 3) * 4096 + (KC) * 64 + (_f >> 2) * 32; \
        float4 _a = *(const float4*)_xp; \
        float4 _b = *(const float4*)(_xp + 4); \
        U4B8 _c; \
        _c.u.x = f2bf(silu_f(_a.x)) | (f2bf(silu_f(_a.y)) << 16); \
        _c.u.y = f2bf(silu_f(_a.z)) | (f2bf(silu_f(_a.w)) << 16); \
        _c.u.z = f2bf(silu_f(_b.x)) | (f2bf(silu_f(_b.y)) << 16); \
        _c.u.w = f2bf(silu_f(_b.z)) | (f2bf(silu_f(_b.w)) << 16); \
        AFC[_f] = _c.v; \
      } \
    } \
    _Pragma("unroll") \
    for (int _ks = 0; _ks < 2; ++_ks) { \
      bf16x8 _b0 = *(const bf16x8*)((const char*)BSC + boff[_ks * 2 + 0]); \
      bf16x8 _b1 = *(const bf16x8*)((const char*)BSC + boff[_ks * 2 + 1]); \
      _Pragma("unroll") \
      for (int _mt = 0; _mt < 4; ++_mt) { \
        acc[_mt][0] = __builtin_amdgcn_mfma_f32_16x16x32_bf16(AFC[_mt + 4 * _ks], _b0, acc[_mt][0], 0, 0, 0); \
        acc[_mt][1] = __builtin_amdgcn_mfma_f32_16x16x32_bf16(AFC[_mt + 4 * _ks], _b1, acc[_mt][1], 0, 0, 0); \
      } \
    } \
    __syncthreads(); }

__launch_bounds__(512, 4)
__global__ void kan_fused(const float* __restrict__ x, const unsigned short* __restrict__ Wc,
                          const bf16x8* __restrict__ T8, float* __restrict__ out) {
    __shared__ __align__(16) unsigned short Bs0[128 * 64];
    __shared__ __align__(16) unsigned short Bs1[128 * 64];

    const int bid = blockIdx.x;
    const int row0 = (bid >> 1) * 128;
    const int col0 = (bid & 1) * 128;
    const int tid = threadIdx.x;
    const int lane = tid & 63;
    const int w = tid >> 6;            // wave 0..7
    const int wm = w >> 2;             // 64-row half
    const int wn = w & 3;              // 32-col quarter
    const int l15 = lane & 15;
    const int q = lane >> 4;

    // B staging mapping (wave covers 16 rows: 2 DMA instrs of 8 rows x 8 segs)
    const int sr = lane >> 3;
    const int s = lane & 7;
    const int g = s ^ sr;              // XOR swizzle: logical k-segment
    const int srow = w * 16 + sr;

    const char* wbase0 = (const char*)(Wc + (size_t)(col0 + srow) * KDIM + g * 8);
    const char* wbase1 = (const char*)(Wc + (size_t)(col0 + srow + 8) * KDIM + g * 8);
    const int ldst0 = (w * 16) * 64;
    const int ldst1 = (w * 16 + 8) * 64;

    // per-lane x base pointers (rows differ by mt*16 -> +mt*4096 floats, uniform)
    const float* xbq = x + (size_t)(row0 + wm * 64 + l15) * IN_F + q;       // basis gathers
    const float* xsl = x + (size_t)(row0 + wm * 64 + l15) * IN_F + q * 8;   // silu frags

    // loop-invariant B ds_read byte offsets: r*128 + ((g0 ^ (r&7))*16), g0 = ks*4+q
    int boff[4];
#pragma unroll
    for (int ks = 0; ks < 2; ++ks)
#pragma unroll
        for (int nt = 0; nt < 2; ++nt) {
            int r = wn * 32 + nt * 16 + l15;
            boff[ks * 2 + nt] = r * 128 + (((ks * 4 + q) ^ (l15 & 7)) << 4);
        }

    f32x4 acc[4][2] = {};
    bf16x8 afA[8], afB[8];

    STAGE_B(0, Bs0)
    __syncthreads();

#pragma unroll 1
    for (int it = 0; it < NCHUNK / 2; ++it) {
        const int kc0 = it * 2;
        CHUNK(kc0, Bs0, Bs1, afA, afB)
        CHUNK(kc0 + 1, Bs1, Bs0, afB, afA)
    }

    // epilogue: C/D layout col = lane&15, row = (lane>>4)*4 + reg
#pragma unroll
    for (int mt = 0; mt < 4; ++mt) {
        int row = row0 + wm * 64 + mt * 16 + q * 4;
#pragma unroll
        for (int nt = 0; nt < 2; ++nt) {
            int col = col0 + wn * 32 + nt * 16 + l15;
#pragma unroll
            for (int r = 0; r < 4; ++r)
                out[(size_t)(row + r) * OUT_F + col] = acc[mt][nt][r];
        }
    }
}

extern "C" void kernel_launch(void* const* d_in, const int* in_sizes, int n_in,
                              void* d_out, int out_size, void* d_ws, size_t ws_size,
                              hipStream_t stream) {
    const float* x  = (const float*)d_in[0];
    const float* bw = (const float*)d_in[1];
    const float* sw = (const float*)d_in[2];
    const float* ss = (const float*)d_in[3];
    unsigned short* Wc = (unsigned short*)d_ws;             // 1.18 MB
    uint4* T = (uint4*)((char*)d_ws + WC_BYTES);            // 22.6 KB direct basis table

    build_w<<<dim3(OUT_F), dim3(IN_F), 0, stream>>>(bw, sw, ss, Wc, T);

    const int B_ROWS = in_sizes[0] / IN_F;                  // 32768
    kan_fused<<<dim3(B_ROWS / 128 * 2), dim3(512), 0, stream>>>(
        x, Wc, (const bf16x8*)T, (float*)d_out);
}

// Round 7
// 152.826 us; speedup vs baseline: 2.1479x; 2.1479x over previous
//
#include <hip/hip_runtime.h>
#include <hip/hip_bf16.h>
#include <stdint.h>

// KANLinear, fused single-pass MFMA GEMM with software-pipelined A-expansion.
//   C = A @ W^T,  A (B x 2304) = [silu(x) | cubic-bspline bases(x)] computed on the fly,
//   W (256 x 2304) = [base_weight | spline_weight*scaler] built once in ws (bf16).
// R7 = R5 (verified 74.6us) + hoisted loop-invariant addressing:
//   - all 12 LDS frag read offsets precomputed (zero VALU in MFMA block)
//   - DMA base pointers + immediate chunk offset
//   - incremental x pointers for the basis region
// NO register double-buffering of fragments (R6's spill disaster).

#define IN_F 256
#define OUT_F 256
#define KDIM 2304 /* 256 silu + 256*8 basis */
#define BK 64
#define NCHUNK (KDIM / BK) /* 36 */
#define WC_BYTES ((size_t)OUT_F * KDIM * 2)

#define AS1 __attribute__((address_space(1)))
#define AS3 __attribute__((address_space(3)))

typedef float f32x4 __attribute__((ext_vector_type(4)));
typedef short bf16x8 __attribute__((ext_vector_type(8)));

__device__ __forceinline__ uint32_t f2bf(float f) {
    union { float f; uint32_t u; } c; c.f = f;
    uint32_t u = c.u;
    return (u + 0x7FFFu + ((u >> 16) & 1u)) >> 16;   // RNE
}

__device__ __forceinline__ float silu_f(float v) {
    return v / (1.0f + __expf(-v));
}

// ---------------- kernel 1: combined bf16 weight ----------------
__global__ void build_w(const float* __restrict__ bw, const float* __restrict__ sw,
                        const float* __restrict__ ss, unsigned short* __restrict__ Wc) {
    const int o = blockIdx.x;
    const int i = threadIdx.x;
    Wc[o * KDIM + i] = (unsigned short)f2bf(bw[o * IN_F + i]);
    const float scal = ss[o * IN_F + i];
    const float4* swv = reinterpret_cast<const float4*>(sw + (size_t)(o * IN_F + i) * 8);
    float4 s0 = swv[0], s1 = swv[1];
    uint4 wv;
    wv.x = f2bf(s0.x * scal) | (f2bf(s0.y * scal) << 16);
    wv.y = f2bf(s0.z * scal) | (f2bf(s0.w * scal) << 16);
    wv.z = f2bf(s1.x * scal) | (f2bf(s1.y * scal) << 16);
    wv.w = f2bf(s1.z * scal) | (f2bf(s1.w * scal) << 16);
    *reinterpret_cast<uint4*>(Wc + o * KDIM + IN_F + i * 8) = wv;
}

// ---------------- kernel 2: fused pipelined GEMM, 512 threads ----------------
// LDS layout per tile: addr(row, g) = row*64 halfwords + ((g ^ (row&7))*8), g = k/8
__launch_bounds__(512, 4)
__global__ void kan_fused(const float* __restrict__ x, const unsigned short* __restrict__ Wc,
                          float* __restrict__ out) {
    __shared__ __align__(16) unsigned short As[2][128 * 64];
    __shared__ __align__(16) unsigned short Bs[2][128 * 64];

    const int bid = blockIdx.x;
    const int row0 = (bid >> 1) * 128;
    const int col0 = (bid & 1) * 128;
    const int tid = threadIdx.x;
    const int lane = tid & 63;
    const int w = tid >> 6;            // wave id 0..7
    const int wm = w >> 2;             // 0..1 : 64-row half
    const int wn = w & 3;              // 0..3 : 32-col quarter
    const int l15 = lane & 15;
    const int q = lane >> 4;

    // staging mapping: each wave covers 16 rows (2 instrs of 8 rows x 8 segments)
    const int sr = lane >> 3;          // row within 8-row group
    const int s  = lane & 7;           // physical 16B segment
    const int g  = s ^ sr;             // logical k-segment held by this thread
    const int srow = w * 16 + sr;      // + j*8, j in {0,1}; (row & 7) == sr

    // ---- hoisted addressing ----
    // DMA source bases (bytes); per chunk add kc*128
    const char* wb0 = (const char*)(Wc + (size_t)(col0 + srow) * KDIM + g * 8);
    const char* wb1 = (const char*)(Wc + (size_t)(col0 + srow + 8) * KDIM + g * 8);
    const int ldst0 = (w * 16) * 64;
    const int ldst1 = (w * 16 + 8) * 64;

    // x pointers: silu region (two row-groups), basis region (incremental)
    const float* xs0 = x + (size_t)(row0 + srow) * IN_F + g * 8;
    const float* xs1 = xs0 + 8 * IN_F;
    const float* xb0 = x + (size_t)(row0 + srow) * IN_F + g;   // advance +8/chunk
    const float* xb1 = xb0 + 8 * IN_F;

    // LDS frag read offsets (halfwords), loop-invariant
    int aoffh[2][4], boffh[2][2];
#pragma unroll
    for (int ks = 0; ks < 2; ++ks) {
        const int g0 = ks * 4 + q;
#pragma unroll
        for (int mt = 0; mt < 4; ++mt) {
            int r = wm * 64 + mt * 16 + l15;
            aoffh[ks][mt] = r * 64 + ((g0 ^ (r & 7)) << 3);
        }
#pragma unroll
        for (int nt = 0; nt < 2; ++nt) {
            int r = wn * 32 + nt * 16 + l15;
            boffh[ks][nt] = r * 64 + ((g0 ^ (r & 7)) << 3);
        }
    }

    f32x4 acc[4][2] = {};
    float xr[2][8];                    // staged x (silu chunks)
    uint64_t pk2[2];                   // packed 4 coefs (basis chunks)
    int j02[2];                        // cell indices (basis chunks)

    auto stage_b = [&](int kc, int buf) {
        __builtin_amdgcn_global_load_lds((const AS1 void*)(wb0 + kc * 128),
                                         (AS3 void*)&Bs[buf][ldst0], 16, 0, 0);
        __builtin_amdgcn_global_load_lds((const AS1 void*)(wb1 + kc * 128),
                                         (AS3 void*)&Bs[buf][ldst1], 16, 0, 0);
    };
    auto load_x = [&](int kc) {
        if (kc < 4) {
            const float* p0 = xs0 + kc * 64;
            const float* p1 = xs1 + kc * 64;
            float4 a0 = *reinterpret_cast<const float4*>(p0);
            float4 b0 = *reinterpret_cast<const float4*>(p0 + 4);
            float4 a1 = *reinterpret_cast<const float4*>(p1);
            float4 b1 = *reinterpret_cast<const float4*>(p1 + 4);
            xr[0][0] = a0.x; xr[0][1] = a0.y; xr[0][2] = a0.z; xr[0][3] = a0.w;
            xr[0][4] = b0.x; xr[0][5] = b0.y; xr[0][6] = b0.z; xr[0][7] = b0.w;
            xr[1][0] = a1.x; xr[1][1] = a1.y; xr[1][2] = a1.z; xr[1][3] = a1.w;
            xr[1][4] = b1.x; xr[1][5] = b1.y; xr[1][6] = b1.z; xr[1][7] = b1.w;
        } else {
            // basis region: one x per row-group; compute packed coefs now
            float xx0 = *xb0;
            float xx1 = *xb1;
            xb0 += 8; xb1 += 8;
#pragma unroll
            for (int j = 0; j < 2; ++j) {
                float xx = j ? xx1 : xx0;
                float u = __builtin_fmaf(xx, 2.5f, 5.5f);   // (x - grid0)/h
                float jf = floorf(u);
                float t = u - jf;
                j02[j] = (int)jf;
                float t2 = t * t, t3 = t2 * t;
                float p3 = t3 * (1.0f / 6.0f);
                float p2 = -0.5f * t3 + 0.5f * t2 + 0.5f * t + (1.0f / 6.0f);
                float p1 = 0.5f * t3 - t2 + (2.0f / 3.0f);
                float omt = 1.0f - t;
                float p0 = omt * omt * omt * (1.0f / 6.0f);
                pk2[j] = (uint64_t)f2bf(p0) | ((uint64_t)f2bf(p1) << 16) |
                         ((uint64_t)f2bf(p2) << 32) | ((uint64_t)f2bf(p3) << 48);
            }
        }
    };
    auto write_a = [&](int kc, int buf) {
        if (kc < 4) {
#pragma unroll
            for (int j = 0; j < 2; ++j) {
                uint4 wv;
                wv.x = f2bf(silu_f(xr[j][0])) | (f2bf(silu_f(xr[j][1])) << 16);
                wv.y = f2bf(silu_f(xr[j][2])) | (f2bf(silu_f(xr[j][3])) << 16);
                wv.z = f2bf(silu_f(xr[j][4])) | (f2bf(silu_f(xr[j][5])) << 16);
                wv.w = f2bf(silu_f(xr[j][6])) | (f2bf(silu_f(xr[j][7])) << 16);
                *reinterpret_cast<uint4*>(&As[buf][(srow + j * 8) * 64 + s * 8]) = wv;
            }
        } else {
#pragma unroll
            for (int j = 0; j < 2; ++j) {
                int j0 = j02[j];
                uint64_t pk = ((unsigned)j0 <= 10u) ? pk2[j] : 0ull;
                int jc = j0 < 0 ? 0 : (j0 > 10 ? 10 : j0);
                int sh = jc * 16 - 48;
                unsigned __int128 v = (unsigned __int128)pk;
                v = (sh >= 0) ? (v << sh) : (v >> (-sh));
                uint4 wv;
                wv.x = (uint32_t)v;
                wv.y = (uint32_t)(v >> 32);
                wv.z = (uint32_t)(v >> 64);
                wv.w = (uint32_t)(v >> 96);
                *reinterpret_cast<uint4*>(&As[buf][(srow + j * 8) * 64 + s * 8]) = wv;
            }
        }
    };

    // prologue
    stage_b(0, 0);
    load_x(0);
    write_a(0, 0);
    __syncthreads();

    for (int kc = 0; kc < NCHUNK; ++kc) {
        const int cur = kc & 1;
        const int nxt = cur ^ 1;
        if (kc + 1 < NCHUNK) {
            stage_b(kc + 1, nxt);   // async DMA, drains at the barrier
            load_x(kc + 1);         // x loads + coef math hide under the MFMA block
        }
#pragma unroll
        for (int ks = 0; ks < 2; ++ks) {
            bf16x8 af[4], bfv[2];
#pragma unroll
            for (int mt = 0; mt < 4; ++mt)
                af[mt] = *reinterpret_cast<const bf16x8*>(&As[cur][aoffh[ks][mt]]);
#pragma unroll
            for (int nt = 0; nt < 2; ++nt)
                bfv[nt] = *reinterpret_cast<const bf16x8*>(&Bs[cur][boffh[ks][nt]]);
#pragma unroll
            for (int mt = 0; mt < 4; ++mt)
#pragma unroll
                for (int nt = 0; nt < 2; ++nt)
                    acc[mt][nt] = __builtin_amdgcn_mfma_f32_16x16x32_bf16(
                        af[mt], bfv[nt], acc[mt][nt], 0, 0, 0);
        }
        if (kc + 1 < NCHUNK) write_a(kc + 1, nxt);
        __syncthreads();
    }

    // epilogue: C/D layout col = lane&15, row = (lane>>4)*4 + reg
    float* outp = out + (size_t)(row0 + wm * 64 + q * 4) * OUT_F + col0 + wn * 32 + l15;
#pragma unroll
    for (int mt = 0; mt < 4; ++mt) {
#pragma unroll
        for (int nt = 0; nt < 2; ++nt) {
#pragma unroll
            for (int r = 0; r < 4; ++r)
                outp[(size_t)(mt * 16 + r) * OUT_F + nt * 16] = acc[mt][nt][r];
        }
    }
}

extern "C" void kernel_launch(void* const* d_in, const int* in_sizes, int n_in,
                              void* d_out, int out_size, void* d_ws, size_t ws_size,
                              hipStream_t stream) {
    const float* x  = (const float*)d_in[0];
    const float* bw = (const float*)d_in[1];
    const float* sw = (const float*)d_in[2];
    const float* ss = (const float*)d_in[3];
    unsigned short* Wc = (unsigned short*)d_ws;   // 1.18 MB

    build_w<<<dim3(OUT_F), dim3(IN_F), 0, stream>>>(bw, sw, ss, Wc);

    const int B_ROWS = in_sizes[0] / IN_F;        // 32768
    kan_fused<<<dim3(B_ROWS / 128 * 2), dim3(512), 0, stream>>>(x, Wc, (float*)d_out);
}

// Round 8
// 150.184 us; speedup vs baseline: 2.1857x; 1.0176x over previous
//
#include <hip/hip_runtime.h>
#include <hip/hip_bf16.h>
#include <stdint.h>

// KANLinear, fused single-pass MFMA GEMM with software-pipelined A-expansion.
//   C = A @ W^T,  A (B x 2304) = [silu(x) | cubic-bspline bases(x)] on the fly,
//   W (256 x 2304) = [base_weight | spline_weight*scaler] built once in ws (bf16).
// R8: block tile 128x256 (FULL N) with 8 waves of 64x64 -> grid 256 = 1 block/CU.
//   - A-expansion + x-fetch done ONCE per element (R5 did it twice, 2 N-tiles)
//   - 64x64 wave tile: 2x FLOP per ds_read_b128 vs R5's 64x32
//   - ping-pong buffers by explicit name (no runtime-index address math)

#define IN_F 256
#define OUT_F 256
#define KDIM 2304 /* 256 silu + 256*8 basis */
#define BK 64
#define NCHUNK (KDIM / BK) /* 36 */
#define WC_BYTES ((size_t)OUT_F * KDIM * 2)

#define AS1 __attribute__((address_space(1)))
#define AS3 __attribute__((address_space(3)))

typedef float f32x4 __attribute__((ext_vector_type(4)));
typedef short bf16x8 __attribute__((ext_vector_type(8)));

__device__ __forceinline__ uint32_t f2bf(float f) {
    union { float f; uint32_t u; } c; c.f = f;
    uint32_t u = c.u;
    return (u + 0x7FFFu + ((u >> 16) & 1u)) >> 16;   // RNE
}

__device__ __forceinline__ float silu_f(float v) {
    return v / (1.0f + __expf(-v));
}

// ---------------- kernel 1: combined bf16 weight ----------------
__global__ void build_w(const float* __restrict__ bw, const float* __restrict__ sw,
                        const float* __restrict__ ss, unsigned short* __restrict__ Wc) {
    const int o = blockIdx.x;
    const int i = threadIdx.x;
    Wc[o * KDIM + i] = (unsigned short)f2bf(bw[o * IN_F + i]);
    const float scal = ss[o * IN_F + i];
    const float4* swv = reinterpret_cast<const float4*>(sw + (size_t)(o * IN_F + i) * 8);
    float4 s0 = swv[0], s1 = swv[1];
    uint4 wv;
    wv.x = f2bf(s0.x * scal) | (f2bf(s0.y * scal) << 16);
    wv.y = f2bf(s0.z * scal) | (f2bf(s0.w * scal) << 16);
    wv.z = f2bf(s1.x * scal) | (f2bf(s1.y * scal) << 16);
    wv.w = f2bf(s1.z * scal) | (f2bf(s1.w * scal) << 16);
    *reinterpret_cast<uint4*>(Wc + o * KDIM + IN_F + i * 8) = wv;
}

// ---------------- kernel 2: fused pipelined GEMM, 128x256 tile ----------------
// LDS layout: addr(row, g) = row*64 halfwords + ((g ^ (row&7))*8), g = k/8
__launch_bounds__(512, 2)
__global__ void kan_fused(const float* __restrict__ x, const unsigned short* __restrict__ Wc,
                          float* __restrict__ out) {
    __shared__ __align__(16) unsigned short As0[128 * 64];
    __shared__ __align__(16) unsigned short As1[128 * 64];
    __shared__ __align__(16) unsigned short Bs0[256 * 64];
    __shared__ __align__(16) unsigned short Bs1[256 * 64];

    const int row0 = blockIdx.x * 128;
    const int tid = threadIdx.x;
    const int lane = tid & 63;
    const int w = tid >> 6;            // wave id 0..7
    const int wm = w >> 2;             // 0..1 : 64-row half
    const int wn = w & 3;              // 0..3 : 64-col quarter
    const int l15 = lane & 15;
    const int q = lane >> 4;

    // staging mapping: 8 rows x 8 segments per instruction
    const int sr = lane >> 3;          // row within 8-row group
    const int s  = lane & 7;           // physical 16B segment
    const int g  = s ^ sr;             // logical k-segment held by this thread
    const int srow = w * 16 + sr;      // A-staging row (+ j*8, j in {0,1}): 0..127

    // B staging: wave w covers rows w*32 .. w*32+31 (4 instrs of 8 rows)
    const int brow = w * 32 + sr;

    // x pointers (A rows 0..127 of this block)
    const float* xs0 = x + (size_t)(row0 + srow) * IN_F + g * 8;
    const float* xs1 = xs0 + 8 * IN_F;

    f32x4 acc[4][4] = {};
    float xr[2][8];                    // staged x (silu chunks)
    uint64_t pk2[2];                   // packed 4 coefs (basis chunks)
    int j02[2];                        // cell indices (basis chunks)

    auto stage_b = [&](int kc, unsigned short* Bsb) {
#pragma unroll
        for (int j = 0; j < 4; ++j) {
            const unsigned short* gp =
                Wc + (size_t)(brow + j * 8) * KDIM + kc * BK + g * 8;
            __builtin_amdgcn_global_load_lds((const AS1 void*)gp,
                                             (AS3 void*)&Bsb[(w * 32 + j * 8) * 64],
                                             16, 0, 0);
        }
    };
    auto load_x = [&](int kc) {
        if (kc < 4) {
            const float* p0 = xs0 + kc * 64;
            const float* p1 = xs1 + kc * 64;
            float4 a0 = *reinterpret_cast<const float4*>(p0);
            float4 b0 = *reinterpret_cast<const float4*>(p0 + 4);
            float4 a1 = *reinterpret_cast<const float4*>(p1);
            float4 b1 = *reinterpret_cast<const float4*>(p1 + 4);
            xr[0][0] = a0.x; xr[0][1] = a0.y; xr[0][2] = a0.z; xr[0][3] = a0.w;
            xr[0][4] = b0.x; xr[0][5] = b0.y; xr[0][6] = b0.z; xr[0][7] = b0.w;
            xr[1][0] = a1.x; xr[1][1] = a1.y; xr[1][2] = a1.z; xr[1][3] = a1.w;
            xr[1][4] = b1.x; xr[1][5] = b1.y; xr[1][6] = b1.z; xr[1][7] = b1.w;
        } else {
            const int i0 = (kc - 4) * 8 + g;
            float xx0 = xs0[i0 - g * 8];   // = x[row0+srow][i0]
            float xx1 = xs1[i0 - g * 8];
#pragma unroll
            for (int j = 0; j < 2; ++j) {
                float xx = j ? xx1 : xx0;
                float u = __builtin_fmaf(xx, 2.5f, 5.5f);   // (x - grid0)/h
                float jf = floorf(u);
                float t = u - jf;
                j02[j] = (int)jf;
                float t2 = t * t, t3 = t2 * t;
                float p3 = t3 * (1.0f / 6.0f);
                float p2 = -0.5f * t3 + 0.5f * t2 + 0.5f * t + (1.0f / 6.0f);
                float p1 = 0.5f * t3 - t2 + (2.0f / 3.0f);
                float omt = 1.0f - t;
                float p0 = omt * omt * omt * (1.0f / 6.0f);
                pk2[j] = (uint64_t)f2bf(p0) | ((uint64_t)f2bf(p1) << 16) |
                         ((uint64_t)f2bf(p2) << 32) | ((uint64_t)f2bf(p3) << 48);
            }
        }
    };
    auto write_a = [&](int kc, unsigned short* Asb) {
        if (kc < 4) {
#pragma unroll
            for (int j = 0; j < 2; ++j) {
                uint4 wv;
                wv.x = f2bf(silu_f(xr[j][0])) | (f2bf(silu_f(xr[j][1])) << 16);
                wv.y = f2bf(silu_f(xr[j][2])) | (f2bf(silu_f(xr[j][3])) << 16);
                wv.z = f2bf(silu_f(xr[j][4])) | (f2bf(silu_f(xr[j][5])) << 16);
                wv.w = f2bf(silu_f(xr[j][6])) | (f2bf(silu_f(xr[j][7])) << 16);
                *reinterpret_cast<uint4*>(&Asb[(srow + j * 8) * 64 + s * 8]) = wv;
            }
        } else {
#pragma unroll
            for (int j = 0; j < 2; ++j) {
                int j0 = j02[j];
                uint64_t pk = ((unsigned)j0 <= 10u) ? pk2[j] : 0ull;
                int jc = j0 < 0 ? 0 : (j0 > 10 ? 10 : j0);
                int sh = jc * 16 - 48;
                unsigned __int128 v = (unsigned __int128)pk;
                v = (sh >= 0) ? (v << sh) : (v >> (-sh));
                uint4 wv;
                wv.x = (uint32_t)v;
                wv.y = (uint32_t)(v >> 32);
                wv.z = (uint32_t)(v >> 64);
                wv.w = (uint32_t)(v >> 96);
                *reinterpret_cast<uint4*>(&Asb[(srow + j * 8) * 64 + s * 8]) = wv;
            }
        }
    };
    auto mfma_chunk = [&](const unsigned short* Asb, const unsigned short* Bsb) {
#pragma unroll
        for (int ks = 0; ks < 2; ++ks) {
            const int g0 = ks * 4 + q;
            bf16x8 af[4], bfv[4];
#pragma unroll
            for (int mt = 0; mt < 4; ++mt) {
                int r = wm * 64 + mt * 16 + l15;
                af[mt] = *reinterpret_cast<const bf16x8*>(
                    &Asb[r * 64 + ((g0 ^ (r & 7)) << 3)]);
            }
#pragma unroll
            for (int nt = 0; nt < 4; ++nt) {
                int r = wn * 64 + nt * 16 + l15;
                bfv[nt] = *reinterpret_cast<const bf16x8*>(
                    &Bsb[r * 64 + ((g0 ^ (r & 7)) << 3)]);
            }
#pragma unroll
            for (int mt = 0; mt < 4; ++mt)
#pragma unroll
                for (int nt = 0; nt < 4; ++nt)
                    acc[mt][nt] = __builtin_amdgcn_mfma_f32_16x16x32_bf16(
                        af[mt], bfv[nt], acc[mt][nt], 0, 0, 0);
        }
    };

#define CHUNK_STEP(KC, ASC, BSC, ASN, BSN)            \
    {                                                 \
        if ((KC) + 1 < NCHUNK) {                      \
            stage_b((KC) + 1, BSN);                   \
            load_x((KC) + 1);                         \
        }                                             \
        mfma_chunk(ASC, BSC);                         \
        if ((KC) + 1 < NCHUNK) write_a((KC) + 1, ASN);\
        __syncthreads();                              \
    }

    // prologue: chunk 0 into buffer 0
    stage_b(0, Bs0);
    load_x(0);
    write_a(0, As0);
    __syncthreads();

#pragma unroll 1
    for (int it = 0; it < NCHUNK / 2; ++it) {
        const int kc0 = it * 2;
        CHUNK_STEP(kc0,     As0, Bs0, As1, Bs1)
        CHUNK_STEP(kc0 + 1, As1, Bs1, As0, Bs0)
    }

    // epilogue: C/D layout col = lane&15, row = (lane>>4)*4 + reg
    float* outp = out + (size_t)(row0 + wm * 64 + q * 4) * OUT_F + wn * 64 + l15;
#pragma unroll
    for (int mt = 0; mt < 4; ++mt) {
#pragma unroll
        for (int nt = 0; nt < 4; ++nt) {
#pragma unroll
            for (int r = 0; r < 4; ++r)
                outp[(size_t)(mt * 16 + r) * OUT_F + nt * 16] = acc[mt][nt][r];
        }
    }
}

extern "C" void kernel_launch(void* const* d_in, const int* in_sizes, int n_in,
                              void* d_out, int out_size, void* d_ws, size_t ws_size,
                              hipStream_t stream) {
    const float* x  = (const float*)d_in[0];
    const float* bw = (const float*)d_in[1];
    const float* sw = (const float*)d_in[2];
    const float* ss = (const float*)d_in[3];
    unsigned short* Wc = (unsigned short*)d_ws;   // 1.18 MB

    build_w<<<dim3(OUT_F), dim3(IN_F), 0, stream>>>(bw, sw, ss, Wc);

    const int B_ROWS = in_sizes[0] / IN_F;        // 32768
    kan_fused<<<dim3(B_ROWS / 128), dim3(512), 0, stream>>>(x, Wc, (float*)d_out);
}